// Round 6
// baseline (53.663 us; speedup 1.0000x reference)
//
#include <hip/hip_runtime.h>

// N=2, L=1024, C=256, H=64, E=16, CL=64, LOUT=960
// qT/kT: [n][h][l][e] fp32 ; vT: [n][h][l] fp32 ; attT: [n][h][l'] fp32

typedef __attribute__((ext_vector_type(8))) __bf16 bf16x8;
typedef __attribute__((ext_vector_type(8))) short short8;
typedef __attribute__((ext_vector_type(4))) float f32x4;

__device__ inline unsigned short bf16_rne(float x) {
    unsigned u = __builtin_bit_cast(unsigned, x);
    unsigned r = u + 0x7fffu + ((u >> 16) & 1u);
    return (unsigned short)(r >> 16);
}
__device__ inline float bf16_f(unsigned short h) {
    return __builtin_bit_cast(float, (unsigned)h << 16);
}

// ---------------------------------------------------------------------------
// Kernel 0: split X and W=[Wq;Wk;Wv] into bf16 hi/lo planes.
// ---------------------------------------------------------------------------
__global__ __launch_bounds__(256) void convert_split(
    const float* __restrict__ X,
    const float* __restrict__ Wq, const float* __restrict__ Wk, const float* __restrict__ Wv,
    unsigned short* __restrict__ XhG, unsigned short* __restrict__ XlG,
    unsigned short* __restrict__ WhG, unsigned short* __restrict__ WlG)
{
    const int g = blockIdx.x * 256 + threadIdx.x;
    const int NX = 131072;
    const int NW = 135168;
    if (g >= NX + NW) return;

    float4 v;
    unsigned short *dh, *dl;
    int off;
    if (g < NX) {
        off = g * 4;
        v = *reinterpret_cast<const float4*>(&X[off]);
        dh = XhG; dl = XlG;
    } else {
        off = (g - NX) * 4;
        const int row = off >> 8, col = off & 255;
        const float* s;
        if (row < 1024)      s = &Wq[row * 256 + col];
        else if (row < 2048) s = &Wk[(row - 1024) * 256 + col];
        else                 s = &Wv[(row - 2048) * 256 + col];
        v = *reinterpret_cast<const float4*>(s);
        dh = WhG; dl = WlG;
    }
    unsigned short h0 = bf16_rne(v.x), h1 = bf16_rne(v.y), h2 = bf16_rne(v.z), h3 = bf16_rne(v.w);
    unsigned short l0 = bf16_rne(v.x - bf16_f(h0));
    unsigned short l1 = bf16_rne(v.y - bf16_f(h1));
    unsigned short l2 = bf16_rne(v.z - bf16_f(h2));
    unsigned short l3 = bf16_rne(v.w - bf16_f(h3));
    ushort4 hv = make_ushort4(h0, h1, h2, h3);
    ushort4 lv = make_ushort4(l0, l1, l2, l3);
    *reinterpret_cast<ushort4*>(&dh[off]) = hv;
    *reinterpret_cast<ushort4*>(&dl[off]) = lv;
}

// ---------------------------------------------------------------------------
// Kernel 1: QKV projection via MFMA, bf16 split-3 (XhWh + XhWl + XlWh).
// 512 thr (8 waves, 2m x 4n). Tile 128x128, k-step 64. LDS 64KB, XOR-swizzled
// via pre-swizzled global source + linear global_load_lds dest (rule 21).
// ---------------------------------------------------------------------------
__device__ __forceinline__ bf16x8 ldsfrag(const unsigned short* lds, int t, int row, int so) {
    return __builtin_bit_cast(bf16x8, *reinterpret_cast<const short8*>(
        lds + t * 8192 + row * 64 + (((so ^ (row & 7)) & 7) << 3)));
}

__global__ __launch_bounds__(512, 4) void qkv_mfma(
    const unsigned short* __restrict__ XhG, const unsigned short* __restrict__ XlG,
    const unsigned short* __restrict__ WhG, const unsigned short* __restrict__ WlG,
    const float* __restrict__ bq, const float* __restrict__ bk, const float* __restrict__ bv,
    float* __restrict__ qT, float* __restrict__ kT, float* __restrict__ vT)
{
    __shared__ unsigned short lds[4 * 128 * 64];   // 64 KB

    const int tid  = threadIdx.x;
    const int lane = tid & 63;
    const int wid  = tid >> 6;
    const int wm   = wid >> 2;
    const int wn   = wid & 3;
    const int m0 = blockIdx.x * 128;
    const int o0 = blockIdx.y * 128;

    f32x4 acc[4][2];
    #pragma unroll
    for (int i = 0; i < 4; ++i)
        #pragma unroll
        for (int j = 0; j < 2; ++j)
            acc[i][j] = f32x4{0.f, 0.f, 0.f, 0.f};

    const int r8 = lane >> 3;
    const int ss = (lane & 7) ^ r8;

    for (int k0 = 0; k0 < 256; k0 += 64) {
        #pragma unroll
        for (int j = 0; j < 8; ++j) {
            const int c   = (wid << 3) | j;
            const int t   = c >> 4;
            const int rg  = c & 15;
            const int row = (rg << 3) + r8;
            const unsigned short* gsrc;
            if (t == 0)      gsrc = &XhG[(m0 + row) * 256 + k0 + (ss << 3)];
            else if (t == 1) gsrc = &XlG[(m0 + row) * 256 + k0 + (ss << 3)];
            else if (t == 2) gsrc = &WhG[(o0 + row) * 256 + k0 + (ss << 3)];
            else             gsrc = &WlG[(o0 + row) * 256 + k0 + (ss << 3)];
            char* lbase = (char*)lds + (c << 10);
            __builtin_amdgcn_global_load_lds(
                (const __attribute__((address_space(1))) void*)gsrc,
                (__attribute__((address_space(3))) void*)lbase, 16, 0, 0);
        }
        __syncthreads();

        #pragma unroll
        for (int kk = 0; kk < 64; kk += 32) {
            const int so = (kk >> 3) + (lane >> 4);
            bf16x8 aH[4], aL[4], bH[2], bL[2];
            #pragma unroll
            for (int mt = 0; mt < 4; ++mt) {
                const int ar = wm * 64 + mt * 16 + (lane & 15);
                aH[mt] = ldsfrag(lds, 0, ar, so);
                aL[mt] = ldsfrag(lds, 1, ar, so);
            }
            #pragma unroll
            for (int ot = 0; ot < 2; ++ot) {
                const int br = wn * 32 + ot * 16 + (lane & 15);
                bH[ot] = ldsfrag(lds, 2, br, so);
                bL[ot] = ldsfrag(lds, 3, br, so);
            }
            #pragma unroll
            for (int mt = 0; mt < 4; ++mt)
                #pragma unroll
                for (int ot = 0; ot < 2; ++ot) {
                    acc[mt][ot] = __builtin_amdgcn_mfma_f32_16x16x32_bf16(aH[mt], bH[ot], acc[mt][ot], 0, 0, 0);
                    acc[mt][ot] = __builtin_amdgcn_mfma_f32_16x16x32_bf16(aH[mt], bL[ot], acc[mt][ot], 0, 0, 0);
                    acc[mt][ot] = __builtin_amdgcn_mfma_f32_16x16x32_bf16(aL[mt], bH[ot], acc[mt][ot], 0, 0, 0);
                }
        }
        __syncthreads();
    }

    const int drow = (lane >> 4) * 4;
    const int dcol = lane & 15;
    const int mode = (o0 < 1024) ? 0 : (o0 < 2048 ? 1 : 2);

    if (mode < 2) {
        float* __restrict__ T = mode ? kT : qT;
        const float* __restrict__ bias = mode ? bk : bq;
        const int ob = mode * 1024;
        #pragma unroll
        for (int ot = 0; ot < 2; ++ot) {
            const int o = o0 + wn * 32 + ot * 16 + dcol;
            const int h = (o >> 4) & 63;
            const int e = o & 15;
            const float bval = bias[o - ob];
            #pragma unroll
            for (int mt = 0; mt < 4; ++mt)
                #pragma unroll
                for (int r = 0; r < 4; ++r) {
                    const int m = m0 + wm * 64 + mt * 16 + drow + r;
                    const int n = m >> 10, l = m & 1023;
                    T[((n * 64 + h) * 1024 + l) * 16 + e] = acc[mt][ot][r] + bval;
                }
        }
    } else if (wn < 2) {
        #pragma unroll
        for (int ot = 0; ot < 2; ++ot) {
            const int hV = wn * 32 + ot * 16 + dcol;
            const float bval = bv[hV];
            #pragma unroll
            for (int mt = 0; mt < 4; ++mt)
                #pragma unroll
                for (int r = 0; r < 4; ++r) {
                    const int m = m0 + wm * 64 + mt * 16 + drow + r;
                    const int n = m >> 10, l = m & 1023;
                    vT[(n * 64 + hV) * 1024 + l] = acc[mt][ot][r] + bval;
                }
        }
    }
}

// ---------------------------------------------------------------------------
// Kernel 2 (v3): sliding-window attention. 256 thr (4 waves), block handles
// (n, h, 256 consecutive outputs) sharing one K/PE/V stage. Lane = output
// position; online exp with fixed shift (exact softmax ratio).
// K rows staged: l0..l0+318 (1.25x over-read vs 2x before).
// ---------------------------------------------------------------------------
__global__ __launch_bounds__(256) void attn_kernel(
    const float* __restrict__ qT, const float* __restrict__ kT,
    const float* __restrict__ vT, const float* __restrict__ PE,
    float* __restrict__ attT)
{
    __shared__ float k_lds[320 * 20];   // 25.6 KB, stride 20 floats (80B)
    __shared__ float pe_lds[64 * 16];
    __shared__ float v_lds[320];

    const int tid  = threadIdx.x;
    const int lane = tid & 63;
    const int w    = tid >> 6;      // 0..3
    const int xb = blockIdx.x;      // 0..3
    const int h  = blockIdx.y;
    const int n  = blockIdx.z;
    const int l0 = xb * 256;

    const int nrows = min(319, 1024 - l0);
    const float4* kb4 = reinterpret_cast<const float4*>(kT + ((size_t)(n * 64 + h) * 1024 + l0) * 16);
    for (int u = tid; u < nrows * 4; u += 256) {
        const int row = u >> 2, f = u & 3;
        *reinterpret_cast<float4*>(&k_lds[row * 20 + f * 4]) = kb4[u];
    }
    {
        const int d = tid >> 2, f = tid & 3;
        *reinterpret_cast<float4*>(&pe_lds[d * 16 + f * 4]) =
            *reinterpret_cast<const float4*>(&PE[(d * 64 + h) * 16 + f * 4]);
    }
    const float* vbase = vT + (size_t)(n * 64 + h) * 1024 + l0;
    for (int u = tid; u < nrows; u += 256) v_lds[u] = vbase[u];

    const int lout = l0 + w * 64 + lane;
    const bool active = lout < 960;
    const int lq = active ? lout : 959;
    float4 q0, q1, q2, q3;
    {
        const float4* qb = reinterpret_cast<const float4*>(
            qT + ((size_t)(n * 64 + h) * 1024 + lq + 32) * 16);
        q0 = qb[0]; q1 = qb[1]; q2 = qb[2]; q3 = qb[3];
    }
    __syncthreads();

    const int rbase = w * 64 + lane;   // local K row base; rbase+63 <= 318 for active
    float den = 0.f, pv = 0.f;
    #pragma unroll 2
    for (int d = 0; d < 64; ++d) {
        const float4* kr = reinterpret_cast<const float4*>(&k_lds[(rbase + d) * 20]);
        const float4* pr = reinterpret_cast<const float4*>(&pe_lds[d * 16]);
        const float4 k0 = kr[0], k1 = kr[1], k2 = kr[2], k3 = kr[3];
        const float4 p0 = pr[0], p1 = pr[1], p2 = pr[2], p3 = pr[3];
        float s0 = (k0.x + p0.x) * q0.x + (k0.y + p0.y) * q0.y
                 + (k0.z + p0.z) * q0.z + (k0.w + p0.w) * q0.w;
        float s1 = (k1.x + p1.x) * q1.x + (k1.y + p1.y) * q1.y
                 + (k1.z + p1.z) * q1.z + (k1.w + p1.w) * q1.w;
        float s2 = (k2.x + p2.x) * q2.x + (k2.y + p2.y) * q2.y
                 + (k2.z + p2.z) * q2.z + (k2.w + p2.w) * q2.w;
        float s3 = (k3.x + p3.x) * q3.x + (k3.y + p3.y) * q3.y
                 + (k3.z + p3.z) * q3.z + (k3.w + p3.w) * q3.w;
        const float s = (s0 + s1) + (s2 + s3);
        const float p = __expf(s - 16.f);
        den += p;
        pv += p * v_lds[rbase + d];
    }
    if (active)
        attT[(size_t)(n * 64 + h) * 960 + lout] = fmaxf(pv / den, 0.f);
}

// ---------------------------------------------------------------------------
// Kernel 3 (v3): 4x FC(64->64, ReLU) + head. 512 thr, 16 rows/block,
// 120 blocks (weights staged once per 16 rows, 4x amortization).
// Thread = (row-pair rr/rr+8, output o). cur-row reads are wave-uniform.
// ---------------------------------------------------------------------------
__global__ __launch_bounds__(512) void fc_kernel(
    const float* __restrict__ attT,
    const float* __restrict__ fc_w, const float* __restrict__ fc_b,
    const float* __restrict__ Wout, const float* __restrict__ bout,
    float* __restrict__ out)
{
    __shared__ float w_lds[64 * 68];
    __shared__ float wo_lds[3 * 64];
    __shared__ float bufA[16 * 68];
    __shared__ float bufB[16 * 68];

    const int tid = threadIdx.x;
    const int o  = tid & 63;
    const int rr = tid >> 6;           // 0..7 (wave id)
    const int blk = blockIdx.x;        // 0..119
    const int n  = blk / 60;
    const int l0 = (blk - n * 60) * 16;
    const int R0 = n * 960 + l0;

    for (int idx = tid; idx < 192; idx += 512) wo_lds[idx] = Wout[idx];
    for (int idx = tid; idx < 1024; idx += 512) {
        const int hh = idx >> 4, r = idx & 15;
        bufA[r * 68 + hh] = attT[(size_t)(n * 64 + hh) * 960 + l0 + r];
    }

    float* cur = bufA;
    float* nxt = bufB;

    for (int layer = 0; layer < 4; ++layer) {
        __syncthreads();
        const float4* wsrc = reinterpret_cast<const float4*>(fc_w + layer * 4096);
        for (int u = tid; u < 1024; u += 512) {
            const int oo = u >> 4, f = u & 15;
            *reinterpret_cast<float4*>(&w_lds[oo * 68 + f * 4]) = wsrc[u];
        }
        __syncthreads();
        const float bias = fc_b[layer * 64 + o];
        const float4* wr = reinterpret_cast<const float4*>(&w_lds[o * 68]);
        #pragma unroll
        for (int rb = 0; rb < 2; ++rb) {
            const int r = rr + rb * 8;
            float acc = bias;
            const float4* cr = reinterpret_cast<const float4*>(&cur[r * 68]);
            #pragma unroll
            for (int t = 0; t < 16; ++t) {
                const float4 c = cr[t], wv = wr[t];
                acc += c.x * wv.x + c.y * wv.y + c.z * wv.z + c.w * wv.w;
            }
            nxt[r * 68 + o] = fmaxf(acc, 0.f);
        }
        float* tmp = cur; cur = nxt; nxt = tmp;
    }
    __syncthreads();

    if (o < 3) {
        #pragma unroll
        for (int rb = 0; rb < 2; ++rb) {
            const int r = rr + rb * 8;
            float acc = bout[o];
            #pragma unroll
            for (int hh = 0; hh < 64; ++hh)
                acc += cur[r * 68 + hh] * wo_lds[o * 64 + hh];
            out[(R0 + r) * 3 + o] = acc;
        }
    }
}

// ---------------------------------------------------------------------------
extern "C" void kernel_launch(void* const* d_in, const int* in_sizes, int n_in,
                              void* d_out, int out_size, void* d_ws, size_t ws_size,
                              hipStream_t stream) {
    const float* x    = (const float*)d_in[0];
    const float* Wq   = (const float*)d_in[1];
    const float* bq   = (const float*)d_in[2];
    const float* Wk   = (const float*)d_in[3];
    const float* bk   = (const float*)d_in[4];
    const float* Wv   = (const float*)d_in[5];
    const float* bv   = (const float*)d_in[6];
    const float* PE   = (const float*)d_in[7];
    const float* fc_w = (const float*)d_in[8];
    const float* fc_b = (const float*)d_in[9];
    const float* Wout = (const float*)d_in[10];
    const float* bout = (const float*)d_in[11];
    float* out = (float*)d_out;

    float* ws = (float*)d_ws;
    float* qT   = ws;                      // 2,097,152 f
    float* kT   = qT + 2097152;            // 2,097,152 f
    float* vT   = kT + 2097152;            // 131,072 f
    float* attT = vT + 131072;             // 122,880 f  [n][h][960]
    unsigned short* XhG = (unsigned short*)(attT + 122880);
    unsigned short* XlG = XhG + 524288;
    unsigned short* WhG = XlG + 524288;
    unsigned short* WlG = WhG + 540672;

    convert_split<<<1040, 256, 0, stream>>>(x, Wq, Wk, Wv, XhG, XlG, WhG, WlG);
    qkv_mfma<<<dim3(16, 17), 512, 0, stream>>>(XhG, XlG, WhG, WlG, bq, bk, bv, qT, kT, vT);
    attn_kernel<<<dim3(4, 64, 2), 256, 0, stream>>>(qT, kT, vT, PE, attT);
    fc_kernel<<<120, 512, 0, stream>>>(attT, fc_w, fc_b, Wout, bout, out);
}